// Round 7
// baseline (488.737 us; speedup 1.0000x reference)
//
#include <hip/hip_runtime.h>
#include <hip/hip_bf16.h>

// TransMatch round 7:
//  - k_score: 256x128 tiles (0.56 KB LDS/MFMA vs 0.75; half the barriers/FLOP)
//  - fc0: k_tr transpose pass + clean gld16 GEMM (k_fc0g); w0 via k_cvt
//  - fc3: packed (a2,c2,w3) float4 table via k_prep
//
// ws layout (float words):
//   Qh   fp16 [16][3072][512]   @ 0          = 12,582,912 f
//   sig  f32  [8][192][192]     @ 12,582,912 =    294,912 f
//   xkey u32  [8][512][192]     @ 12,877,824 =    786,432 f
//   w0h  fp16 [8][512][512]     @ 13,664,256 =  1,048,576 f
//   fT   fp16 [16][3072][512]   @ 14,712,832 = 12,582,912 f   (dies after k_fc0g)
//   xh   fp16 [8][512][192]     @ 14,712,832 (alias fT) =   393,216 f
//   w2h  fp16 [8][2048][192]    @ 15,106,048 (alias fT) = 1,572,864 f
//   hb   fp16 [8][512][2048]    @ 16,678,912 (alias fT) = 4,194,304 f
//   bn2sum f32 [8][2048]        @ 20,873,216 =     16,384 f
//   bn2sq  f32 [8][2048]        @ 20,889,600 =     16,384 f
//   bn1acc f32 [8][2]           @ 20,905,984 =         16 f
//   ybuf f32 [8][512]           @ 20,906,000 =      4,096 f
//   tbl  f32x4 [8][2048]        @ 20,910,096 =     65,536 f
// total 27,295,744 f = 109.2 MB

#define EPS_ 1e-5f

typedef __attribute__((ext_vector_type(8))) _Float16 fp16x8;
typedef __attribute__((ext_vector_type(4)))  float   f32x4;
typedef __attribute__((ext_vector_type(16))) float   f32x16;

__device__ __forceinline__ unsigned fkey(float f) {
    unsigned u = __float_as_uint(f);
    return (u & 0x80000000u) ? ~u : (u | 0x80000000u);
}
__device__ __forceinline__ float funkey(unsigned k) {
    return (k & 0x80000000u) ? __uint_as_float(k & 0x7FFFFFFFu)
                             : __uint_as_float(~k);
}
__device__ __forceinline__ void gld16(const void* gp, void* lp) {
    __builtin_amdgcn_global_load_lds(
        (const __attribute__((address_space(1))) unsigned*)gp,
        (__attribute__((address_space(3))) unsigned*)lp, 16, 0, 0);
}

// ---------------- K0: sig = sigmoid(se) ----------------
__global__ __launch_bounds__(256) void k_sig(const float* __restrict__ se,
                                             float* __restrict__ sig) {
    int i = blockIdx.x * 256 + threadIdx.x;
    float4 v = *(const float4*)(se + (size_t)i * 4);
    float4 o;
    o.x = 1.f / (1.f + __expf(-v.x));
    o.y = 1.f / (1.f + __expf(-v.y));
    o.z = 1.f / (1.f + __expf(-v.z));
    o.w = 1.f / (1.f + __expf(-v.w));
    *(float4*)(sig + (size_t)i * 4) = o;
}

// ---------------- K0b: generic fp32 -> fp16 convert ----------------
__global__ __launch_bounds__(256) void k_cvt(const float* __restrict__ src,
                                             _Float16* __restrict__ dst) {
    int i = blockIdx.x * 256 + threadIdx.x;
    float4 v = *(const float4*)(src + (size_t)i * 4);
    _Float16 h[4] = {(_Float16)v.x, (_Float16)v.y, (_Float16)v.z, (_Float16)v.w};
    *(uint2*)(dst + (size_t)i * 4) = *(uint2*)h;
}

// ---------------- K1a: transpose+convert feat -> fT[(sel,l)][b*192+t][d] ----
// Block: one (sel, l, b, d-chunk of 128). LDS tile [192 t][128 d] fp16,
// row stride 272 B (16-aligned for phase-2 b128 reads).
__global__ __launch_bounds__(256) void k_tr(const float* __restrict__ qfeat,
                                            const float* __restrict__ gfeat,
                                            _Float16* __restrict__ fT) {
    int bid = blockIdx.x;
    int dc = bid & 3;  bid >>= 2;
    int b  = bid & 15; bid >>= 4;
    int l  = bid & 7;  bid >>= 3;
    int sel = bid;
    const float* feat = (sel ? gfeat : qfeat) + (size_t)b * 786432 + (size_t)(l * 512 + dc * 128) * 192;

    __shared__ __align__(16) char T[192 * 272];
    int tid = threadIdx.x;
    int tl = tid & 63;
    int dg = tid >> 6;          // 0..3 -> d pair base dg*2

    // phase 1: coalesced fp32 reads along t, packed b32 writes to T[t][d]
    #pragma unroll
    for (int ds = 0; ds < 16; ds++) {
        int d = ds * 8 + dg * 2;
        #pragma unroll
        for (int ts = 0; ts < 3; ts++) {
            int t = ts * 64 + tl;
            float v0 = feat[(size_t)d * 192 + t];
            float v1 = feat[(size_t)(d + 1) * 192 + t];
            _Float16 h2[2] = {(_Float16)v0, (_Float16)v1};
            *(unsigned*)(T + t * 272 + d * 2) = *(unsigned*)h2;
        }
    }
    __syncthreads();
    // phase 2: coalesced 16-B writes of fT rows
    _Float16* ob = fT + (size_t)(sel * 8 + l) * 1572864 + (size_t)b * 98304 + dc * 128;
    #pragma unroll
    for (int ws = 0; ws < 12; ws++) {
        int flat = ws * 256 + tid;          // 192 rows x 16 chunks
        int row = flat >> 4;
        int ch = flat & 15;
        uint4 v = *(const uint4*)(T + row * 272 + ch * 16);
        *(uint4*)(ob + (size_t)row * 512 + ch * 8) = v;
    }
}

// ---------------- K1b: fc0 GEMM  Qh[m][e] = fT[m,:] . w0h[e,:] + b0 --------
// Per (sel,l): M=3072, N=512, K=512. 128x128 tiles, gld16 staging, swizzled.
__global__ __launch_bounds__(256) void k_fc0g(const _Float16* __restrict__ fT,
                                              const _Float16* __restrict__ w0h,
                                              const float* __restrict__ b0,
                                              _Float16* __restrict__ Qh) {
    int bid = blockIdx.x;
    int sl = bid / 96;                  // sel*8+l
    int rem = bid - sl * 96;
    int mt = rem >> 2, nt = rem & 3;
    int m0 = mt * 128, n0 = nt * 128;
    int l = sl & 7;
    const char* Ag = (const char*)(fT + (size_t)sl * 1572864);
    const char* Bg = (const char*)(w0h + (size_t)l * 262144);

    __shared__ __align__(16) char As[8192];
    __shared__ __align__(16) char Bs[8192];

    int tid = threadIdx.x;
    int lane = tid & 63;
    int w = tid >> 6;
    int wm = w >> 1, wn = w & 1;

    f32x4 acc[4][4];
    #pragma unroll
    for (int mi = 0; mi < 4; mi++)
        #pragma unroll
        for (int nj = 0; nj < 4; nj++)
            #pragma unroll
            for (int r = 0; r < 4; r++) acc[mi][nj][r] = 0.f;

    int srow = lane >> 2;
    int sseg = ((lane & 3) ^ ((lane >> 3) & 3)) * 16;
    int c = lane & 15;
    int kqp = (((lane >> 4) ^ ((c >> 1) & 3))) * 16;

    for (int d0 = 0; d0 < 1024; d0 += 64) {
        __syncthreads();
        #pragma unroll
        for (int j = 0; j < 2; j++) {
            int r = w * 32 + j * 16 + srow;
            gld16(Ag + (size_t)(m0 + r) * 1024 + d0 + sseg, As + (w * 32 + j * 16) * 64);
            gld16(Bg + (size_t)(n0 + r) * 1024 + d0 + sseg, Bs + (w * 32 + j * 16) * 64);
        }
        __syncthreads();
        fp16x8 a[4], b[4];
        #pragma unroll
        for (int mi = 0; mi < 4; mi++)
            a[mi] = *(const fp16x8*)(As + (wm * 64 + mi * 16 + c) * 64 + kqp);
        #pragma unroll
        for (int nj = 0; nj < 4; nj++)
            b[nj] = *(const fp16x8*)(Bs + (wn * 64 + nj * 16 + c) * 64 + kqp);
        #pragma unroll
        for (int mi = 0; mi < 4; mi++)
            #pragma unroll
            for (int nj = 0; nj < 4; nj++)
                acc[mi][nj] = __builtin_amdgcn_mfma_f32_16x16x32_f16(a[mi], b[nj], acc[mi][nj], 0, 0, 0);
    }

    int rq = (lane >> 4) * 4;
    _Float16* ob = Qh + (size_t)sl * 1572864;
    #pragma unroll
    for (int nj = 0; nj < 4; nj++) {
        int e = n0 + wn * 64 + nj * 16 + c;
        float bias = b0[l * 512 + e];
        #pragma unroll
        for (int mi = 0; mi < 4; mi++) {
            #pragma unroll
            for (int r = 0; r < 4; r++) {
                int m = m0 + wm * 64 + mi * 16 + rq + r;
                ob[(size_t)m * 512 + e] = (_Float16)(acc[mi][nj][r] + bias);
            }
        }
    }
}

// ---------------- K2: score GEMM 256x128 + fused sig/max ----------------
// C[gm,gn] = Key[gm,:].Query[gn,:], gm = k*192+s (256 rows), gn = q*192+t (128).
// 4 waves 2x2: wave = 128 rows x 64 cols -> 8x4 frags of 16x16x32.
__global__ __launch_bounds__(256) void k_score(const _Float16* __restrict__ Qh,
                                               const float* __restrict__ sig,
                                               unsigned* __restrict__ xkey) {
    int bid = blockIdx.x;
    int l = bid / 288;
    int rem = bid - l * 288;
    int grp = rem / 48;                 // 6 groups of 4 nt
    int within = rem - grp * 48;
    int mt = within >> 2;               // 12
    int nt = grp * 4 + (within & 3);    // 24
    int m0 = mt * 256, n0 = nt * 128;

    const char* Ag = (const char*)(Qh + (size_t)(8 + l) * 1572864);   // key
    const char* Bg = (const char*)(Qh + (size_t)l * 1572864);         // query
    const float* sg = sig + (size_t)l * 36864;

    __shared__ __align__(16) char As[16384];     // 256 rows x 64 B
    __shared__ __align__(16) char Bs[8192];      // 128 rows x 64 B
    __shared__ unsigned tmax[4][128];            // [row-64-group][col]
    __shared__ unsigned smax[2][256];            // [col-64-seg][row]

    int tid = threadIdx.x;
    int lane = tid & 63;
    int w = tid >> 6;
    int wm = w >> 1, wn = w & 1;

    f32x4 acc[8][4];
    #pragma unroll
    for (int mi = 0; mi < 8; mi++)
        #pragma unroll
        for (int nj = 0; nj < 4; nj++)
            #pragma unroll
            for (int r = 0; r < 4; r++) acc[mi][nj][r] = 0.f;

    int srow = lane >> 2;
    int sseg = ((lane & 3) ^ ((lane >> 3) & 3)) * 16;
    int c = lane & 15;
    int kqp = (((lane >> 4) ^ ((c >> 1) & 3))) * 16;

    for (int d0 = 0; d0 < 1024; d0 += 64) {
        __syncthreads();
        #pragma unroll
        for (int j = 0; j < 4; j++) {      // A: wave stages 64 rows
            int r = w * 64 + j * 16 + srow;
            gld16(Ag + (size_t)(m0 + r) * 1024 + d0 + sseg, As + (w * 64 + j * 16) * 64);
        }
        #pragma unroll
        for (int j = 0; j < 2; j++) {      // B: wave stages 32 rows
            int r = w * 32 + j * 16 + srow;
            gld16(Bg + (size_t)(n0 + r) * 1024 + d0 + sseg, Bs + (w * 32 + j * 16) * 64);
        }
        __syncthreads();
        fp16x8 b[4];
        #pragma unroll
        for (int nj = 0; nj < 4; nj++)
            b[nj] = *(const fp16x8*)(Bs + (wn * 64 + nj * 16 + c) * 64 + kqp);
        #pragma unroll
        for (int mi = 0; mi < 8; mi++) {
            fp16x8 a = *(const fp16x8*)(As + (wm * 128 + mi * 16 + c) * 64 + kqp);
            #pragma unroll
            for (int nj = 0; nj < 4; nj++)
                acc[mi][nj] = __builtin_amdgcn_mfma_f32_16x16x32_f16(a, b[nj], acc[mi][nj], 0, 0, 0);
        }
    }

    // ---- epilogue: v = C * sig[s,t]; per-s max over t, per-t max over s ----
    int sb_w = m0 + wm * 128;           // this wave's global row base
    int tb_w = (n0 + wn * 64) % 192;    // t base (64-seg within one q)
    int rq = (lane >> 4) * 4;

    float rowm[8][4];
    float colm[2][4];
    #pragma unroll
    for (int mi = 0; mi < 8; mi++)
        #pragma unroll
        for (int r = 0; r < 4; r++) rowm[mi][r] = -3.4e38f;
    #pragma unroll
    for (int g = 0; g < 2; g++)
        #pragma unroll
        for (int nj = 0; nj < 4; nj++) colm[g][nj] = -3.4e38f;

    #pragma unroll
    for (int mi = 0; mi < 8; mi++) {
        int g = mi >> 2;
        int sRow = (sb_w + mi * 16) % 192;       // multiple of 16
        #pragma unroll
        for (int r = 0; r < 4; r++) {
            int s = sRow + rq + r;
            const float* sp = sg + (size_t)s * 192 + tb_w;
            #pragma unroll
            for (int nj = 0; nj < 4; nj++) {
                float m = sp[nj * 16 + c];
                float v = acc[mi][nj][r] * m;
                rowm[mi][r] = fmaxf(rowm[mi][r], v);
                colm[g][nj] = fmaxf(colm[g][nj], v);
            }
        }
    }
    #pragma unroll
    for (int g = 0; g < 2; g++)
        #pragma unroll
        for (int nj = 0; nj < 4; nj++) {
            colm[g][nj] = fmaxf(colm[g][nj], __shfl_xor(colm[g][nj], 16));
            colm[g][nj] = fmaxf(colm[g][nj], __shfl_xor(colm[g][nj], 32));
        }
    if (lane < 16) {
        #pragma unroll
        for (int g = 0; g < 2; g++)
            #pragma unroll
            for (int nj = 0; nj < 4; nj++)
                tmax[wm * 2 + g][wn * 64 + nj * 16 + lane] = fkey(colm[g][nj]);
    }
    #pragma unroll
    for (int st = 1; st <= 8; st <<= 1)
        #pragma unroll
        for (int mi = 0; mi < 8; mi++)
            #pragma unroll
            for (int r = 0; r < 4; r++)
                rowm[mi][r] = fmaxf(rowm[mi][r], __shfl_xor(rowm[mi][r], st));
    if (c == 0) {
        #pragma unroll
        for (int mi = 0; mi < 8; mi++)
            #pragma unroll
            for (int r = 0; r < 4; r++)
                smax[wn][wm * 128 + mi * 16 + rq + r] = fkey(rowm[mi][r]);
    }
    __syncthreads();

    // flush 1024 entries -> global
    #pragma unroll
    for (int rep = 0; rep < 4; rep++) {
        int idx = tid + rep * 256;
        if (idx < 512) {                 // tmax: (g, col)
            int g = idx >> 7, col = idx & 127;
            int kk = (m0 + g * 64) / 192;
            int q = (n0 + col) / 192, t = (n0 + col) % 192;
            atomicMax(&xkey[((size_t)l * 512 + 2 * (q * 16 + kk)) * 192 + t], tmax[g][col]);
        } else {                         // smax: (wnf, row)
            int i2 = idx - 512;
            int wnf = i2 >> 8, row = i2 & 255;
            int q = (n0 + wnf * 64) / 192;
            int kk = (m0 + row) / 192, s = (m0 + row) % 192;
            atomicMax(&xkey[((size_t)l * 512 + 2 * (q * 16 + kk) + 1) * 192 + s], smax[wnf][row]);
        }
    }
}

// ---------------- K3a: bn1 partial stats ----------------
__global__ __launch_bounds__(256) void k_bn1s(const unsigned* __restrict__ xkey,
                                              float* __restrict__ bn1acc) {
    int l = blockIdx.x / 48;
    int b = blockIdx.x - l * 48;
    const unsigned* xk = xkey + (size_t)l * 98304 + b * 2048;
    int tid = threadIdx.x;
    uint4 v1 = *(const uint4*)(xk + tid * 8);
    uint4 v2 = *(const uint4*)(xk + tid * 8 + 4);
    float s = 0.f, s2 = 0.f;
    float e;
    e = funkey(v1.x); s += e; s2 += e * e;
    e = funkey(v1.y); s += e; s2 += e * e;
    e = funkey(v1.z); s += e; s2 += e * e;
    e = funkey(v1.w); s += e; s2 += e * e;
    e = funkey(v2.x); s += e; s2 += e * e;
    e = funkey(v2.y); s += e; s2 += e * e;
    e = funkey(v2.z); s += e; s2 += e * e;
    e = funkey(v2.w); s += e; s2 += e * e;
    #pragma unroll
    for (int o = 32; o; o >>= 1) { s += __shfl_down(s, o); s2 += __shfl_down(s2, o); }
    if ((tid & 63) == 0) {
        atomicAdd(&bn1acc[l * 2], s);
        atomicAdd(&bn1acc[l * 2 + 1], s2);
    }
}

// ---------------- K3b: bn1 normalize -> fp16 x ----------------
__global__ __launch_bounds__(256) void k_bn1n(const unsigned* __restrict__ xkey,
                                              const float* __restrict__ bn1acc,
                                              const float* __restrict__ g1,
                                              const float* __restrict__ b1,
                                              _Float16* __restrict__ xh) {
    int idx = blockIdx.x * 256 + threadIdx.x;
    int l = idx / 24576;
    float mu = bn1acc[l * 2] * (1.f / 98304.f);
    float var = bn1acc[l * 2 + 1] * (1.f / 98304.f) - mu * mu;
    float a1 = g1[l] * rsqrtf(var + EPS_);
    float c1 = b1[l] - mu * a1;
    uint4 kv = *(const uint4*)(xkey + (size_t)idx * 4);
    _Float16 h[4];
    h[0] = (_Float16)(funkey(kv.x) * a1 + c1);
    h[1] = (_Float16)(funkey(kv.y) * a1 + c1);
    h[2] = (_Float16)(funkey(kv.z) * a1 + c1);
    h[3] = (_Float16)(funkey(kv.w) * a1 + c1);
    *(uint2*)(xh + (size_t)idx * 4) = *(uint2*)h;
}

// ---------------- K4: fc2 fp16 GEMM + fused bn2 partial stats ----------------
__global__ __launch_bounds__(256) void k_fc2(const _Float16* __restrict__ xh,
                                             const _Float16* __restrict__ w2h,
                                             const float* __restrict__ b2,
                                             _Float16* __restrict__ hb,
                                             float* __restrict__ bn2sum,
                                             float* __restrict__ bn2sq) {
    int bid = blockIdx.x;
    int l = bid >> 6;
    int rem = bid & 63;
    int mt = rem & 3, nt = rem >> 2;
    int m0 = mt * 128, n0 = nt * 128;
    const char* Ag = (const char*)(xh + (size_t)l * 98304);
    const char* Bg = (const char*)(w2h + (size_t)l * 393216);

    __shared__ __align__(16) char As[8192];
    __shared__ __align__(16) char Bs[8192];

    int tid = threadIdx.x;
    int lane = tid & 63;
    int w = tid >> 6;
    int wm = w >> 1, wn = w & 1;

    f32x4 acc[4][4];
    #pragma unroll
    for (int mi = 0; mi < 4; mi++)
        #pragma unroll
        for (int nj = 0; nj < 4; nj++)
            #pragma unroll
            for (int r = 0; r < 4; r++) acc[mi][nj][r] = 0.f;

    int srow = lane >> 2;
    int sseg = ((lane & 3) ^ ((lane >> 3) & 3)) * 16;
    int c = lane & 15;
    int kqp = (((lane >> 4) ^ ((c >> 1) & 3))) * 16;

    for (int d0 = 0; d0 < 384; d0 += 64) {
        __syncthreads();
        #pragma unroll
        for (int j = 0; j < 2; j++) {
            int r = w * 32 + j * 16 + srow;
            gld16(Ag + (size_t)(m0 + r) * 384 + d0 + sseg, As + (w * 32 + j * 16) * 64);
            gld16(Bg + (size_t)(n0 + r) * 384 + d0 + sseg, Bs + (w * 32 + j * 16) * 64);
        }
        __syncthreads();
        fp16x8 a[4], b[4];
        #pragma unroll
        for (int mi = 0; mi < 4; mi++)
            a[mi] = *(const fp16x8*)(As + (wm * 64 + mi * 16 + c) * 64 + kqp);
        #pragma unroll
        for (int nj = 0; nj < 4; nj++)
            b[nj] = *(const fp16x8*)(Bs + (wn * 64 + nj * 16 + c) * 64 + kqp);
        #pragma unroll
        for (int mi = 0; mi < 4; mi++)
            #pragma unroll
            for (int nj = 0; nj < 4; nj++)
                acc[mi][nj] = __builtin_amdgcn_mfma_f32_16x16x32_f16(a[mi], b[nj], acc[mi][nj], 0, 0, 0);
    }

    int rq = (lane >> 4) * 4;
    _Float16* ho = hb + (size_t)l * 1048576;
    float colsum[4], colsq[4];
    #pragma unroll
    for (int nj = 0; nj < 4; nj++) { colsum[nj] = 0.f; colsq[nj] = 0.f; }
    #pragma unroll
    for (int nj = 0; nj < 4; nj++) {
        int gf = n0 + wn * 64 + nj * 16 + c;
        float bias = b2[l * 2048 + gf];
        #pragma unroll
        for (int mi = 0; mi < 4; mi++) {
            #pragma unroll
            for (int r = 0; r < 4; r++) {
                int gm = m0 + wm * 64 + mi * 16 + rq + r;
                float v = acc[mi][nj][r] + bias;
                ho[(size_t)gm * 2048 + gf] = (_Float16)v;
                colsum[nj] += v;
                colsq[nj] += v * v;
            }
        }
    }
    #pragma unroll
    for (int nj = 0; nj < 4; nj++) {
        colsum[nj] += __shfl_xor(colsum[nj], 16);
        colsum[nj] += __shfl_xor(colsum[nj], 32);
        colsq[nj]  += __shfl_xor(colsq[nj], 16);
        colsq[nj]  += __shfl_xor(colsq[nj], 32);
    }
    if (lane < 16) {
        #pragma unroll
        for (int nj = 0; nj < 4; nj++) {
            int gf = n0 + wn * 64 + nj * 16 + lane;
            atomicAdd(&bn2sum[l * 2048 + gf], colsum[nj]);
            atomicAdd(&bn2sq[l * 2048 + gf], colsq[nj]);
        }
    }
}

// ---------------- K5: pack bn2/fc3 params ----------------
__global__ __launch_bounds__(256) void k_prep(const float* __restrict__ bn2sum,
                                              const float* __restrict__ bn2sq,
                                              const float* __restrict__ g2,
                                              const float* __restrict__ bb2,
                                              const float* __restrict__ w3,
                                              float4* __restrict__ tbl) {
    int i = blockIdx.x * 256 + threadIdx.x;   // 16384
    float mu = bn2sum[i] * (1.f / 512.f);
    float var = bn2sq[i] * (1.f / 512.f) - mu * mu;
    float a2 = g2[i] * rsqrtf(var + EPS_);
    float c2 = bb2[i] - mu * a2;
    tbl[i] = make_float4(a2, c2, w3[i], 0.f);
}

// ---------------- K6: bn2 + relu + fc3 dot ----------------
__global__ __launch_bounds__(256) void k_fc3(const _Float16* __restrict__ hb,
                                             const float4* __restrict__ tbl,
                                             const float* __restrict__ b3,
                                             float* __restrict__ ybuf) {
    int n = blockIdx.x & 511;
    int l = blockIdx.x >> 9;
    const _Float16* h = hb + ((size_t)l * 512 + n) * 2048;
    int tid = threadIdx.x;
    int f0 = tid * 8;
    fp16x8 hv = *(const fp16x8*)(h + f0);
    const float4* tb = tbl + l * 2048 + f0;
    float sum = 0.f;
    #pragma unroll
    for (int j = 0; j < 8; j++) {
        float4 p = tb[j];
        float v = fmaf((float)hv[j], p.x, p.y);
        v = fmaxf(v, 0.f);
        sum += v * p.z;
    }
    __shared__ float red[4];
    int lane = tid & 63, w = tid >> 6;
    #pragma unroll
    for (int o = 32; o; o >>= 1) sum += __shfl_down(sum, o);
    if (lane == 0) red[w] = sum;
    __syncthreads();
    if (tid == 0) ybuf[l * 512 + n] = red[0] + red[1] + red[2] + red[3] + b3[l];
}

// ---------------- K7: pair-sum + bn3 + layer-sum + pair_labels ----------------
__global__ __launch_bounds__(256) void k_final(const float* __restrict__ ybuf,
                                               const float* __restrict__ g3,
                                               const float* __restrict__ bb3,
                                               const int* __restrict__ targets,
                                               float* __restrict__ out) {
    int tid = threadIdx.x;
    __shared__ float red[8];
    float scoreacc = 0.f;
    for (int l = 0; l < 8; l++) {
        float z = ybuf[l * 512 + 2 * tid] + ybuf[l * 512 + 2 * tid + 1];
        float s = z, s2 = z * z;
        int lane = tid & 63, w = tid >> 6;
        #pragma unroll
        for (int o = 32; o; o >>= 1) { s += __shfl_down(s, o); s2 += __shfl_down(s2, o); }
        if (lane == 0) { red[w] = s; red[4 + w] = s2; }
        __syncthreads();
        float S1 = red[0] + red[1] + red[2] + red[3];
        float S2 = red[4] + red[5] + red[6] + red[7];
        float mu = S1 * (1.f / 256.f);
        float var = S2 * (1.f / 256.f) - mu * mu;
        float rstd = rsqrtf(var + EPS_);
        scoreacc += g3[l] * (z - mu) * rstd + bb3[l];
        __syncthreads();
    }
    out[tid] = scoreacc;
    int i = tid >> 4, j = tid & 15;
    out[256 + tid] = (targets[i] == targets[j]) ? 1.f : 0.f;
}

extern "C" void kernel_launch(void* const* d_in, const int* in_sizes, int n_in,
                              void* d_out, int out_size, void* d_ws, size_t ws_size,
                              hipStream_t stream) {
    const float* q_feat = (const float*)d_in[0];
    const float* g_feat = (const float*)d_in[1];
    const int*   targets = (const int*)d_in[2];
    const float* se     = (const float*)d_in[3];
    const float* fc0_w  = (const float*)d_in[4];
    const float* fc0_b  = (const float*)d_in[5];
    const float* bn1_g  = (const float*)d_in[6];
    const float* bn1_b  = (const float*)d_in[7];
    const float* fc2_w  = (const float*)d_in[8];
    const float* fc2_b  = (const float*)d_in[9];
    const float* bn2_g  = (const float*)d_in[10];
    const float* bn2_b  = (const float*)d_in[11];
    const float* fc3_w  = (const float*)d_in[12];
    const float* fc3_b  = (const float*)d_in[13];
    const float* bn3_g  = (const float*)d_in[14];
    const float* bn3_b  = (const float*)d_in[15];

    float* ws = (float*)d_ws;
    _Float16* Qh   = (_Float16*)ws;                      // @0
    float*    sig  = ws + 12582912;
    unsigned* xkey = (unsigned*)(ws + 12877824);
    _Float16* w0h  = (_Float16*)(ws + 13664256);
    _Float16* fT   = (_Float16*)(ws + 14712832);         // dies after k_fc0g
    _Float16* xh   = (_Float16*)(ws + 14712832);         // alias (post-fc0)
    _Float16* w2h  = (_Float16*)(ws + 15106048);         // alias (post-fc0)
    _Float16* hb   = (_Float16*)(ws + 16678912);         // alias (post-fc0)
    float* bn2sum = ws + 20873216;
    float* bn2sq  = ws + 20889600;
    float* bn1acc = ws + 20905984;
    float* ybuf   = ws + 20906000;
    float4* tbl   = (float4*)(ws + 20910096);
    float* out  = (float*)d_out;

    hipMemsetAsync(xkey, 0, 786432 * sizeof(unsigned), stream);
    k_sig<<<288, 256, 0, stream>>>(se, sig);
    k_cvt<<<2048, 256, 0, stream>>>(fc0_w, w0h);
    k_tr<<<1024, 256, 0, stream>>>(q_feat, g_feat, fT);
    k_fc0g<<<1536, 256, 0, stream>>>(fT, w0h, fc0_b, Qh);
    k_cvt<<<3072, 256, 0, stream>>>(fc2_w, w2h);          // after fc0 (aliases fT)
    k_score<<<2304, 256, 0, stream>>>(Qh, sig, xkey);
    hipMemsetAsync(bn2sum, 0, 32784 * sizeof(float), stream);  // bn2sum+bn2sq+bn1acc
    k_bn1s<<<384, 256, 0, stream>>>(xkey, bn1acc);
    k_bn1n<<<768, 256, 0, stream>>>(xkey, bn1acc, bn1_g, bn1_b, xh);
    k_fc2<<<512, 256, 0, stream>>>(xh, w2h, fc2_b, hb, bn2sum, bn2sq);
    k_prep<<<64, 256, 0, stream>>>(bn2sum, bn2sq, bn2_g, bn2_b, fc3_w, tbl);
    k_fc3<<<4096, 256, 0, stream>>>(hb, tbl, fc3_b, ybuf);
    k_final<<<1, 256, 0, stream>>>(ybuf, bn3_g, bn3_b, targets, out);
}

// Round 8
// 437.417 us; speedup vs baseline: 1.1173x; 1.1173x over previous
//
#include <hip/hip_runtime.h>
#include <hip/hip_bf16.h>

// TransMatch round 8:
//  - Revert k_score to 128x128 (round-6 occupancy), but BK=64 (128-B chunks):
//    half the barrier/vmcnt-drain count. 8-chunk XOR swizzle (q ^ (r&7)):
//    fragment b128 reads 2-way (free), staging source-permuted, coalesced.
//  - Same BK=64 treatment for k_fc0g (8 iters) and k_fc2 (3 iters).
//
// ws layout (float words): same as round 7.

#define EPS_ 1e-5f

typedef __attribute__((ext_vector_type(8))) _Float16 fp16x8;
typedef __attribute__((ext_vector_type(4)))  float   f32x4;

__device__ __forceinline__ unsigned fkey(float f) {
    unsigned u = __float_as_uint(f);
    return (u & 0x80000000u) ? ~u : (u | 0x80000000u);
}
__device__ __forceinline__ float funkey(unsigned k) {
    return (k & 0x80000000u) ? __uint_as_float(k & 0x7FFFFFFFu)
                             : __uint_as_float(~k);
}
__device__ __forceinline__ void gld16(const void* gp, void* lp) {
    __builtin_amdgcn_global_load_lds(
        (const __attribute__((address_space(1))) unsigned*)gp,
        (__attribute__((address_space(3))) unsigned*)lp, 16, 0, 0);
}

// ---------------- K0: sig = sigmoid(se) ----------------
__global__ __launch_bounds__(256) void k_sig(const float* __restrict__ se,
                                             float* __restrict__ sig) {
    int i = blockIdx.x * 256 + threadIdx.x;
    float4 v = *(const float4*)(se + (size_t)i * 4);
    float4 o;
    o.x = 1.f / (1.f + __expf(-v.x));
    o.y = 1.f / (1.f + __expf(-v.y));
    o.z = 1.f / (1.f + __expf(-v.z));
    o.w = 1.f / (1.f + __expf(-v.w));
    *(float4*)(sig + (size_t)i * 4) = o;
}

// ---------------- K0b: generic fp32 -> fp16 convert ----------------
__global__ __launch_bounds__(256) void k_cvt(const float* __restrict__ src,
                                             _Float16* __restrict__ dst) {
    int i = blockIdx.x * 256 + threadIdx.x;
    float4 v = *(const float4*)(src + (size_t)i * 4);
    _Float16 h[4] = {(_Float16)v.x, (_Float16)v.y, (_Float16)v.z, (_Float16)v.w};
    *(uint2*)(dst + (size_t)i * 4) = *(uint2*)h;
}

// ---------------- K1a: transpose+convert feat -> fT ----------------
__global__ __launch_bounds__(256) void k_tr(const float* __restrict__ qfeat,
                                            const float* __restrict__ gfeat,
                                            _Float16* __restrict__ fT) {
    int bid = blockIdx.x;
    int dc = bid & 3;  bid >>= 2;
    int b  = bid & 15; bid >>= 4;
    int l  = bid & 7;  bid >>= 3;
    int sel = bid;
    const float* feat = (sel ? gfeat : qfeat) + (size_t)b * 786432 + (size_t)(l * 512 + dc * 128) * 192;

    __shared__ __align__(16) char T[192 * 272];
    int tid = threadIdx.x;
    int tl = tid & 63;
    int dg = tid >> 6;

    #pragma unroll
    for (int ds = 0; ds < 16; ds++) {
        int d = ds * 8 + dg * 2;
        #pragma unroll
        for (int ts = 0; ts < 3; ts++) {
            int t = ts * 64 + tl;
            float v0 = feat[(size_t)d * 192 + t];
            float v1 = feat[(size_t)(d + 1) * 192 + t];
            _Float16 h2[2] = {(_Float16)v0, (_Float16)v1};
            *(unsigned*)(T + t * 272 + d * 2) = *(unsigned*)h2;
        }
    }
    __syncthreads();
    _Float16* ob = fT + (size_t)(sel * 8 + l) * 1572864 + (size_t)b * 98304 + dc * 128;
    #pragma unroll
    for (int ws = 0; ws < 12; ws++) {
        int flat = ws * 256 + tid;
        int row = flat >> 4;
        int ch = flat & 15;
        uint4 v = *(const uint4*)(T + row * 272 + ch * 16);
        *(uint4*)(ob + (size_t)row * 512 + ch * 8) = v;
    }
}

// ---------------- K1b: fc0 GEMM (BK=64) ----------------
__global__ __launch_bounds__(256) void k_fc0g(const _Float16* __restrict__ fT,
                                              const _Float16* __restrict__ w0h,
                                              const float* __restrict__ b0,
                                              _Float16* __restrict__ Qh) {
    int bid = blockIdx.x;
    int sl = bid / 96;
    int rem = bid - sl * 96;
    int mt = rem >> 2, nt = rem & 3;
    int m0 = mt * 128, n0 = nt * 128;
    int l = sl & 7;
    const char* Ag = (const char*)(fT + (size_t)sl * 1572864);
    const char* Bg = (const char*)(w0h + (size_t)l * 262144);

    __shared__ __align__(16) char As[16384];   // 128 rows x 128 B
    __shared__ __align__(16) char Bs[16384];

    int tid = threadIdx.x;
    int lane = tid & 63;
    int w = tid >> 6;
    int wm = w >> 1, wn = w & 1;

    f32x4 acc[4][4];
    #pragma unroll
    for (int mi = 0; mi < 4; mi++)
        #pragma unroll
        for (int nj = 0; nj < 4; nj++)
            #pragma unroll
            for (int r = 0; r < 4; r++) acc[mi][nj][r] = 0.f;

    int srow8 = lane >> 3;          // 0..7
    int ssoff = ((lane & 7) ^ srow8) * 16;
    int c = lane & 15;
    int q4 = lane >> 4;             // 0..3
    int c7 = c & 7;

    for (int d0 = 0; d0 < 1024; d0 += 128) {
        __syncthreads();
        #pragma unroll
        for (int j = 0; j < 4; j++) {
            int r = w * 32 + j * 8 + srow8;
            gld16(Ag + (size_t)(m0 + r) * 1024 + d0 + ssoff, As + (w * 32 + j * 8) * 128);
            gld16(Bg + (size_t)(n0 + r) * 1024 + d0 + ssoff, Bs + (w * 32 + j * 8) * 128);
        }
        __syncthreads();
        #pragma unroll
        for (int ks = 0; ks < 2; ks++) {
            int off = ((ks * 4 + q4) ^ c7) * 16;
            fp16x8 a[4], b[4];
            #pragma unroll
            for (int mi = 0; mi < 4; mi++)
                a[mi] = *(const fp16x8*)(As + (wm * 64 + mi * 16 + c) * 128 + off);
            #pragma unroll
            for (int nj = 0; nj < 4; nj++)
                b[nj] = *(const fp16x8*)(Bs + (wn * 64 + nj * 16 + c) * 128 + off);
            #pragma unroll
            for (int mi = 0; mi < 4; mi++)
                #pragma unroll
                for (int nj = 0; nj < 4; nj++)
                    acc[mi][nj] = __builtin_amdgcn_mfma_f32_16x16x32_f16(a[mi], b[nj], acc[mi][nj], 0, 0, 0);
        }
    }

    int rq = (lane >> 4) * 4;
    _Float16* ob = Qh + (size_t)sl * 1572864;
    #pragma unroll
    for (int nj = 0; nj < 4; nj++) {
        int e = n0 + wn * 64 + nj * 16 + c;
        float bias = b0[l * 512 + e];
        #pragma unroll
        for (int mi = 0; mi < 4; mi++) {
            #pragma unroll
            for (int r = 0; r < 4; r++) {
                int m = m0 + wm * 64 + mi * 16 + rq + r;
                ob[(size_t)m * 512 + e] = (_Float16)(acc[mi][nj][r] + bias);
            }
        }
    }
}

// ---------------- K2: score GEMM 128x128 BK=64 + fused sig/max ----------------
__global__ __launch_bounds__(256) void k_score(const _Float16* __restrict__ Qh,
                                               const float* __restrict__ sig,
                                               unsigned* __restrict__ xkey) {
    int bid = blockIdx.x;
    int l = bid / 576;
    int rem = bid - l * 576;
    int grp = rem / 96;
    int within = rem - grp * 96;
    int mt = within >> 2;
    int nt = grp * 4 + (within & 3);
    int m0 = mt * 128, n0 = nt * 128;

    const char* Ag = (const char*)(Qh + (size_t)(8 + l) * 1572864);   // key
    const char* Bg = (const char*)(Qh + (size_t)l * 1572864);         // query
    const float* sg = sig + (size_t)l * 36864;

    __shared__ __align__(16) char As[16384];
    __shared__ __align__(16) char Bs[16384];
    __shared__ unsigned tmaxL[4][64];
    __shared__ unsigned smaxL[4][64];

    int tid = threadIdx.x;
    int lane = tid & 63;
    int w = tid >> 6;
    int wm = w >> 1, wn = w & 1;

    f32x4 acc[4][4];
    #pragma unroll
    for (int mi = 0; mi < 4; mi++)
        #pragma unroll
        for (int nj = 0; nj < 4; nj++)
            #pragma unroll
            for (int r = 0; r < 4; r++) acc[mi][nj][r] = 0.f;

    int srow8 = lane >> 3;
    int ssoff = ((lane & 7) ^ srow8) * 16;
    int c = lane & 15;
    int q4 = lane >> 4;
    int c7 = c & 7;

    for (int d0 = 0; d0 < 1024; d0 += 128) {
        __syncthreads();
        #pragma unroll
        for (int j = 0; j < 4; j++) {
            int r = w * 32 + j * 8 + srow8;
            gld16(Ag + (size_t)(m0 + r) * 1024 + d0 + ssoff, As + (w * 32 + j * 8) * 128);
            gld16(Bg + (size_t)(n0 + r) * 1024 + d0 + ssoff, Bs + (w * 32 + j * 8) * 128);
        }
        __syncthreads();
        #pragma unroll
        for (int ks = 0; ks < 2; ks++) {
            int off = ((ks * 4 + q4) ^ c7) * 16;
            fp16x8 a[4], b[4];
            #pragma unroll
            for (int mi = 0; mi < 4; mi++)
                a[mi] = *(const fp16x8*)(As + (wm * 64 + mi * 16 + c) * 128 + off);
            #pragma unroll
            for (int nj = 0; nj < 4; nj++)
                b[nj] = *(const fp16x8*)(Bs + (wn * 64 + nj * 16 + c) * 128 + off);
            #pragma unroll
            for (int mi = 0; mi < 4; mi++)
                #pragma unroll
                for (int nj = 0; nj < 4; nj++)
                    acc[mi][nj] = __builtin_amdgcn_mfma_f32_16x16x32_f16(a[mi], b[nj], acc[mi][nj], 0, 0, 0);
        }
    }

    // ---- epilogue: v = C * sig[s,t]; per-s max over t, per-t max over s ----
    int gmb = m0 + wm * 64;
    int sb = gmb % 192;
    int gnb = n0 + wn * 64;
    int tb = gnb % 192;
    int rq = (lane >> 4) * 4;

    float rowm[4][4];
    float colm[4];
    #pragma unroll
    for (int mi = 0; mi < 4; mi++)
        #pragma unroll
        for (int r = 0; r < 4; r++) rowm[mi][r] = -3.4e38f;
    #pragma unroll
    for (int nj = 0; nj < 4; nj++) colm[nj] = -3.4e38f;

    #pragma unroll
    for (int mi = 0; mi < 4; mi++) {
        #pragma unroll
        for (int r = 0; r < 4; r++) {
            int s = sb + mi * 16 + rq + r;
            const float* srow_p = sg + (size_t)s * 192 + tb;
            #pragma unroll
            for (int nj = 0; nj < 4; nj++) {
                float m = srow_p[nj * 16 + c];
                float v = acc[mi][nj][r] * m;
                rowm[mi][r] = fmaxf(rowm[mi][r], v);
                colm[nj] = fmaxf(colm[nj], v);
            }
        }
    }
    #pragma unroll
    for (int nj = 0; nj < 4; nj++) {
        colm[nj] = fmaxf(colm[nj], __shfl_xor(colm[nj], 16));
        colm[nj] = fmaxf(colm[nj], __shfl_xor(colm[nj], 32));
    }
    if (lane < 16) {
        #pragma unroll
        for (int nj = 0; nj < 4; nj++)
            tmaxL[wm * 2 + wn][nj * 16 + lane] = fkey(colm[nj]);
    }
    #pragma unroll
    for (int st = 1; st <= 8; st <<= 1)
        #pragma unroll
        for (int mi = 0; mi < 4; mi++)
            #pragma unroll
            for (int r = 0; r < 4; r++)
                rowm[mi][r] = fmaxf(rowm[mi][r], __shfl_xor(rowm[mi][r], st));
    if (c == 0) {
        #pragma unroll
        for (int mi = 0; mi < 4; mi++)
            #pragma unroll
            for (int r = 0; r < 4; r++)
                smaxL[wm * 2 + wn][mi * 16 + rq + r] = fkey(rowm[mi][r]);
    }
    __syncthreads();

    #pragma unroll
    for (int rep = 0; rep < 2; rep++) {
        int idx = tid + rep * 256;
        int wp = idx >> 7;
        int which = (idx >> 6) & 1;
        int off = idx & 63;
        int wmf = wp >> 1, wnf = wp & 1;
        int kf = (m0 + wmf * 64) / 192, sbf = (m0 + wmf * 64) % 192;
        int qf = (n0 + wnf * 64) / 192, tbf = (n0 + wnf * 64) % 192;
        int jp = qf * 16 + kf;
        if (which == 0)
            atomicMax(&xkey[((size_t)l * 512 + 2 * jp) * 192 + tbf + off], tmaxL[wp][off]);
        else
            atomicMax(&xkey[((size_t)l * 512 + 2 * jp + 1) * 192 + sbf + off], smaxL[wp][off]);
    }
}

// ---------------- K3a: bn1 partial stats ----------------
__global__ __launch_bounds__(256) void k_bn1s(const unsigned* __restrict__ xkey,
                                              float* __restrict__ bn1acc) {
    int l = blockIdx.x / 48;
    int b = blockIdx.x - l * 48;
    const unsigned* xk = xkey + (size_t)l * 98304 + b * 2048;
    int tid = threadIdx.x;
    uint4 v1 = *(const uint4*)(xk + tid * 8);
    uint4 v2 = *(const uint4*)(xk + tid * 8 + 4);
    float s = 0.f, s2 = 0.f;
    float e;
    e = funkey(v1.x); s += e; s2 += e * e;
    e = funkey(v1.y); s += e; s2 += e * e;
    e = funkey(v1.z); s += e; s2 += e * e;
    e = funkey(v1.w); s += e; s2 += e * e;
    e = funkey(v2.x); s += e; s2 += e * e;
    e = funkey(v2.y); s += e; s2 += e * e;
    e = funkey(v2.z); s += e; s2 += e * e;
    e = funkey(v2.w); s += e; s2 += e * e;
    #pragma unroll
    for (int o = 32; o; o >>= 1) { s += __shfl_down(s, o); s2 += __shfl_down(s2, o); }
    if ((tid & 63) == 0) {
        atomicAdd(&bn1acc[l * 2], s);
        atomicAdd(&bn1acc[l * 2 + 1], s2);
    }
}

// ---------------- K3b: bn1 normalize -> fp16 x ----------------
__global__ __launch_bounds__(256) void k_bn1n(const unsigned* __restrict__ xkey,
                                              const float* __restrict__ bn1acc,
                                              const float* __restrict__ g1,
                                              const float* __restrict__ b1,
                                              _Float16* __restrict__ xh) {
    int idx = blockIdx.x * 256 + threadIdx.x;
    int l = idx / 24576;
    float mu = bn1acc[l * 2] * (1.f / 98304.f);
    float var = bn1acc[l * 2 + 1] * (1.f / 98304.f) - mu * mu;
    float a1 = g1[l] * rsqrtf(var + EPS_);
    float c1 = b1[l] - mu * a1;
    uint4 kv = *(const uint4*)(xkey + (size_t)idx * 4);
    _Float16 h[4];
    h[0] = (_Float16)(funkey(kv.x) * a1 + c1);
    h[1] = (_Float16)(funkey(kv.y) * a1 + c1);
    h[2] = (_Float16)(funkey(kv.z) * a1 + c1);
    h[3] = (_Float16)(funkey(kv.w) * a1 + c1);
    *(uint2*)(xh + (size_t)idx * 4) = *(uint2*)h;
}

// ---------------- K4: fc2 fp16 GEMM (BK=64, 3 iters) + fused bn2 stats -------
__global__ __launch_bounds__(256) void k_fc2(const _Float16* __restrict__ xh,
                                             const _Float16* __restrict__ w2h,
                                             const float* __restrict__ b2,
                                             _Float16* __restrict__ hb,
                                             float* __restrict__ bn2sum,
                                             float* __restrict__ bn2sq) {
    int bid = blockIdx.x;
    int l = bid >> 6;
    int rem = bid & 63;
    int mt = rem & 3, nt = rem >> 2;
    int m0 = mt * 128, n0 = nt * 128;
    const char* Ag = (const char*)(xh + (size_t)l * 98304);     // rows 384 B
    const char* Bg = (const char*)(w2h + (size_t)l * 393216);

    __shared__ __align__(16) char As[16384];
    __shared__ __align__(16) char Bs[16384];

    int tid = threadIdx.x;
    int lane = tid & 63;
    int w = tid >> 6;
    int wm = w >> 1, wn = w & 1;

    f32x4 acc[4][4];
    #pragma unroll
    for (int mi = 0; mi < 4; mi++)
        #pragma unroll
        for (int nj = 0; nj < 4; nj++)
            #pragma unroll
            for (int r = 0; r < 4; r++) acc[mi][nj][r] = 0.f;

    int srow8 = lane >> 3;
    int ssoff = ((lane & 7) ^ srow8) * 16;
    int c = lane & 15;
    int q4 = lane >> 4;
    int c7 = c & 7;

    for (int d0 = 0; d0 < 384; d0 += 128) {
        __syncthreads();
        #pragma unroll
        for (int j = 0; j < 4; j++) {
            int r = w * 32 + j * 8 + srow8;
            gld16(Ag + (size_t)(m0 + r) * 384 + d0 + ssoff, As + (w * 32 + j * 8) * 128);
            gld16(Bg + (size_t)(n0 + r) * 384 + d0 + ssoff, Bs + (w * 32 + j * 8) * 128);
        }
        __syncthreads();
        #pragma unroll
        for (int ks = 0; ks < 2; ks++) {
            int off = ((ks * 4 + q4) ^ c7) * 16;
            fp16x8 a[4], b[4];
            #pragma unroll
            for (int mi = 0; mi < 4; mi++)
                a[mi] = *(const fp16x8*)(As + (wm * 64 + mi * 16 + c) * 128 + off);
            #pragma unroll
            for (int nj = 0; nj < 4; nj++)
                b[nj] = *(const fp16x8*)(Bs + (wn * 64 + nj * 16 + c) * 128 + off);
            #pragma unroll
            for (int mi = 0; mi < 4; mi++)
                #pragma unroll
                for (int nj = 0; nj < 4; nj++)
                    acc[mi][nj] = __builtin_amdgcn_mfma_f32_16x16x32_f16(a[mi], b[nj], acc[mi][nj], 0, 0, 0);
        }
    }

    int rq = (lane >> 4) * 4;
    _Float16* ho = hb + (size_t)l * 1048576;
    float colsum[4], colsq[4];
    #pragma unroll
    for (int nj = 0; nj < 4; nj++) { colsum[nj] = 0.f; colsq[nj] = 0.f; }
    #pragma unroll
    for (int nj = 0; nj < 4; nj++) {
        int gf = n0 + wn * 64 + nj * 16 + c;
        float bias = b2[l * 2048 + gf];
        #pragma unroll
        for (int mi = 0; mi < 4; mi++) {
            #pragma unroll
            for (int r = 0; r < 4; r++) {
                int gm = m0 + wm * 64 + mi * 16 + rq + r;
                float v = acc[mi][nj][r] + bias;
                ho[(size_t)gm * 2048 + gf] = (_Float16)v;
                colsum[nj] += v;
                colsq[nj] += v * v;
            }
        }
    }
    #pragma unroll
    for (int nj = 0; nj < 4; nj++) {
        colsum[nj] += __shfl_xor(colsum[nj], 16);
        colsum[nj] += __shfl_xor(colsum[nj], 32);
        colsq[nj]  += __shfl_xor(colsq[nj], 16);
        colsq[nj]  += __shfl_xor(colsq[nj], 32);
    }
    if (lane < 16) {
        #pragma unroll
        for (int nj = 0; nj < 4; nj++) {
            int gf = n0 + wn * 64 + nj * 16 + lane;
            atomicAdd(&bn2sum[l * 2048 + gf], colsum[nj]);
            atomicAdd(&bn2sq[l * 2048 + gf], colsq[nj]);
        }
    }
}

// ---------------- K5: pack bn2/fc3 params ----------------
__global__ __launch_bounds__(256) void k_prep(const float* __restrict__ bn2sum,
                                              const float* __restrict__ bn2sq,
                                              const float* __restrict__ g2,
                                              const float* __restrict__ bb2,
                                              const float* __restrict__ w3,
                                              float4* __restrict__ tbl) {
    int i = blockIdx.x * 256 + threadIdx.x;
    float mu = bn2sum[i] * (1.f / 512.f);
    float var = bn2sq[i] * (1.f / 512.f) - mu * mu;
    float a2 = g2[i] * rsqrtf(var + EPS_);
    float c2 = bb2[i] - mu * a2;
    tbl[i] = make_float4(a2, c2, w3[i], 0.f);
}

// ---------------- K6: bn2 + relu + fc3 dot ----------------
__global__ __launch_bounds__(256) void k_fc3(const _Float16* __restrict__ hb,
                                             const float4* __restrict__ tbl,
                                             const float* __restrict__ b3,
                                             float* __restrict__ ybuf) {
    int n = blockIdx.x & 511;
    int l = blockIdx.x >> 9;
    const _Float16* h = hb + ((size_t)l * 512 + n) * 2048;
    int tid = threadIdx.x;
    int f0 = tid * 8;
    fp16x8 hv = *(const fp16x8*)(h + f0);
    const float4* tb = tbl + l * 2048 + f0;
    float sum = 0.f;
    #pragma unroll
    for (int j = 0; j < 8; j++) {
        float4 p = tb[j];
        float v = fmaf((float)hv[j], p.x, p.y);
        v = fmaxf(v, 0.f);
        sum += v * p.z;
    }
    __shared__ float red[4];
    int lane = tid & 63, w = tid >> 6;
    #pragma unroll
    for (int o = 32; o; o >>= 1) sum += __shfl_down(sum, o);
    if (lane == 0) red[w] = sum;
    __syncthreads();
    if (tid == 0) ybuf[l * 512 + n] = red[0] + red[1] + red[2] + red[3] + b3[l];
}

// ---------------- K7: pair-sum + bn3 + layer-sum + pair_labels ----------------
__global__ __launch_bounds__(256) void k_final(const float* __restrict__ ybuf,
                                               const float* __restrict__ g3,
                                               const float* __restrict__ bb3,
                                               const int* __restrict__ targets,
                                               float* __restrict__ out) {
    int tid = threadIdx.x;
    __shared__ float red[8];
    float scoreacc = 0.f;
    for (int l = 0; l < 8; l++) {
        float z = ybuf[l * 512 + 2 * tid] + ybuf[l * 512 + 2 * tid + 1];
        float s = z, s2 = z * z;
        int lane = tid & 63, w = tid >> 6;
        #pragma unroll
        for (int o = 32; o; o >>= 1) { s += __shfl_down(s, o); s2 += __shfl_down(s2, o); }
        if (lane == 0) { red[w] = s; red[4 + w] = s2; }
        __syncthreads();
        float S1 = red[0] + red[1] + red[2] + red[3];
        float S2 = red[4] + red[5] + red[6] + red[7];
        float mu = S1 * (1.f / 256.f);
        float var = S2 * (1.f / 256.f) - mu * mu;
        float rstd = rsqrtf(var + EPS_);
        scoreacc += g3[l] * (z - mu) * rstd + bb3[l];
        __syncthreads();
    }
    out[tid] = scoreacc;
    int i = tid >> 4, j = tid & 15;
    out[256 + tid] = (targets[i] == targets[j]) ? 1.f : 0.f;
}

extern "C" void kernel_launch(void* const* d_in, const int* in_sizes, int n_in,
                              void* d_out, int out_size, void* d_ws, size_t ws_size,
                              hipStream_t stream) {
    const float* q_feat = (const float*)d_in[0];
    const float* g_feat = (const float*)d_in[1];
    const int*   targets = (const int*)d_in[2];
    const float* se     = (const float*)d_in[3];
    const float* fc0_w  = (const float*)d_in[4];
    const float* fc0_b  = (const float*)d_in[5];
    const float* bn1_g  = (const float*)d_in[6];
    const float* bn1_b  = (const float*)d_in[7];
    const float* fc2_w  = (const float*)d_in[8];
    const float* fc2_b  = (const float*)d_in[9];
    const float* bn2_g  = (const float*)d_in[10];
    const float* bn2_b  = (const float*)d_in[11];
    const float* fc3_w  = (const float*)d_in[12];
    const float* fc3_b  = (const float*)d_in[13];
    const float* bn3_g  = (const float*)d_in[14];
    const float* bn3_b  = (const float*)d_in[15];

    float* ws = (float*)d_ws;
    _Float16* Qh   = (_Float16*)ws;
    float*    sig  = ws + 12582912;
    unsigned* xkey = (unsigned*)(ws + 12877824);
    _Float16* w0h  = (_Float16*)(ws + 13664256);
    _Float16* fT   = (_Float16*)(ws + 14712832);
    _Float16* xh   = (_Float16*)(ws + 14712832);         // alias (post-fc0)
    _Float16* w2h  = (_Float16*)(ws + 15106048);         // alias (post-fc0)
    _Float16* hb   = (_Float16*)(ws + 16678912);         // alias (post-fc0)
    float* bn2sum = ws + 20873216;
    float* bn2sq  = ws + 20889600;
    float* bn1acc = ws + 20905984;
    float* ybuf   = ws + 20906000;
    float4* tbl   = (float4*)(ws + 20910096);
    float* out  = (float*)d_out;

    hipMemsetAsync(xkey, 0, 786432 * sizeof(unsigned), stream);
    k_sig<<<288, 256, 0, stream>>>(se, sig);
    k_cvt<<<2048, 256, 0, stream>>>(fc0_w, w0h);
    k_tr<<<1024, 256, 0, stream>>>(q_feat, g_feat, fT);
    k_fc0g<<<1536, 256, 0, stream>>>(fT, w0h, fc0_b, Qh);
    k_cvt<<<3072, 256, 0, stream>>>(fc2_w, w2h);          // after fc0 (aliases fT)
    k_score<<<4608, 256, 0, stream>>>(Qh, sig, xkey);
    hipMemsetAsync(bn2sum, 0, 32784 * sizeof(float), stream);
    k_bn1s<<<384, 256, 0, stream>>>(xkey, bn1acc);
    k_bn1n<<<768, 256, 0, stream>>>(xkey, bn1acc, bn1_g, bn1_b, xh);
    k_fc2<<<512, 256, 0, stream>>>(xh, w2h, fc2_b, hb, bn2sum, bn2sq);
    k_prep<<<64, 256, 0, stream>>>(bn2sum, bn2sq, bn2_g, bn2_b, fc3_w, tbl);
    k_fc3<<<4096, 256, 0, stream>>>(hb, tbl, fc3_b, ybuf);
    k_final<<<1, 256, 0, stream>>>(ybuf, bn3_g, bn3_b, targets, out);
}